// Round 16
// baseline (1467.115 us; speedup 1.0000x reference)
//
#include <hip/hip_runtime.h>

#define Hdim 256
static const int E_N  = 260640;
static const int NG_N = 65160;
static const int NM_N = 40962;

typedef __attribute__((ext_vector_type(8))) __bf16 bf16x8;
typedef __attribute__((ext_vector_type(8))) unsigned short u16x8;
typedef __attribute__((ext_vector_type(4))) float f32x4;

__device__ __forceinline__ unsigned short f2bf(float f) {
  unsigned u = __float_as_uint(f);
  u = (u + 0x7FFFu + ((u >> 16) & 1u)) >> 16;
  return (unsigned short)u;
}
__device__ __forceinline__ float bf2f(unsigned short h) {
  return __uint_as_float((unsigned)h << 16);
}
struct BfPair { unsigned short hi, lo; };
__device__ __forceinline__ BfPair split2(float f) {
  BfPair r;
  r.hi = f2bf(f);
  r.lo = f2bf(f - bf2f(r.hi));
  return r;
}
__device__ __forceinline__ BfPair split2t(float f) {
  unsigned u = __float_as_uint(f);
  BfPair r;
  r.hi = (unsigned short)(u >> 16);
  r.lo = f2bf(f - __uint_as_float(u & 0xffff0000u));
  return r;
}
__device__ __forceinline__ int hswz(int row) {
  return ((row & 7) << 3) ^ (((row >> 2) & 3) << 4);
}
__device__ __forceinline__ void bar_lds() {
  asm volatile("s_waitcnt lgkmcnt(0)" ::: "memory");
  __builtin_amdgcn_s_barrier();
}

// W [K][N=256] f32 -> fragment-major split-bf16 (see R12)
__global__ void wfrag_kernel(const float* __restrict__ W,
                             unsigned short* __restrict__ Fh,
                             unsigned short* __restrict__ Fl, int K, int N) {
  int i = blockIdx.x * 256 + threadIdx.x;
  if (i >= K * N) return;
  int k = i / N;
  int col = i - k * N;
  BfPair p = split2(W[i]);
  int t = k >> 5, rem = k & 31;
  int lg = rem >> 3, j = rem & 7;
  int cb = col >> 4, lr = col & 15;
  long o = ((long)(t * 16 + cb) * 64 + (lg * 16 + lr)) * 8 + j;
  Fh[o] = p.hi;
  Fl[o] = p.lo;
}

// ---- CSR permutation build: order[] = edge ids sorted by dst ----
__global__ void hist_kernel(const int* __restrict__ dst, int* __restrict__ cnt, int E) {
  int i = blockIdx.x * 256 + threadIdx.x;
  if (i < E) atomicAdd(&cnt[dst[i]], 1);
}
__global__ void scan_kernel(const int* __restrict__ cnt, int* __restrict__ off2, int n) {
  __shared__ int ts[1024];
  const int tid = threadIdx.x;
  const int per = (n + 1023) >> 10;
  const int lo = tid * per;
  const int hi = min(lo + per, n);
  int s = 0;
  for (int i = lo; i < hi; ++i) s += cnt[i];
  ts[tid] = s;
  __syncthreads();
  for (int d = 1; d < 1024; d <<= 1) {
    int v = (tid >= d) ? ts[tid - d] : 0;
    __syncthreads();
    ts[tid] += v;
    __syncthreads();
  }
  int base = (tid == 0) ? 0 : ts[tid - 1];
  for (int i = lo; i < hi; ++i) {
    off2[i] = base;
    base += cnt[i];
  }
}
__global__ void fill_kernel(const int* __restrict__ dst, int* __restrict__ off2,
                            int* __restrict__ order, int E) {
  int i = blockIdx.x * 256 + threadIdx.x;
  if (i < E) {
    int pos = atomicAdd(&off2[dst[i]], 1);
    order[pos] = i;
  }
}

// edge (A3=false): union(ahi, lnp) + hh = 51.2 KB -> 3 blocks/CU
// grid/mesh (A3=true): + alo = 69.6 KB -> 2 blocks/CU
template <bool A3>
struct SMem {
  union {
    unsigned short ahi[2][64][72];
    float lnp[4][64][2];
  } u;
  unsigned short alo[A3 ? 2 : 1][A3 ? 64 : 1][A3 ? 72 : 1];
  unsigned short hh[64 * 256];             // XOR-swizzled rows
};

// out = LN(silu(cat(segs)@W1+b1)@W2+b2)*g+b  [+residual | atomic scatter]
// ord != nullptr: process rows in permuted (dst-sorted) order.
template <int NSEG, bool SCATTER, bool A3>
__launch_bounds__(256, A3 ? 2 : 3)
__global__ void mlp_mfma(
    const float* s0, const float* s1, const float* s2,
    const int* __restrict__ i1, const int* __restrict__ i2, int M,
    const unsigned short* __restrict__ W1Fh, const unsigned short* __restrict__ W1Fl,
    const float* __restrict__ b1,
    const unsigned short* __restrict__ W2Fh, const unsigned short* __restrict__ W2Fl,
    const float* __restrict__ b2,
    const float* __restrict__ gamma, const float* __restrict__ beta,
    const float* residual, float* outp,
    float* agg, const int* __restrict__ scat, const int* __restrict__ ord) {
  constexpr int K1 = NSEG * 256;
  constexpr int NT = K1 / 32;
  constexpr int NU = K1 / 64;
  __shared__ SMem<A3> sm;

  const int tid = threadIdx.x;
  const int w = tid >> 6;
  const int l = tid & 63;
  const int lr = l & 15;
  const int lg = l >> 4;
  const int colbase = w * 64 + lr;
  const long blockRow = (long)blockIdx.x * 64;

  const long grow_s = blockRow + l;
  const long growc = grow_s < M ? grow_s : (long)(M - 1);
  const long erow = ord ? (long)ord[growc] : growc;
  const float* rp0 = s0 + erow * Hdim;
  const float* rp1 = nullptr;
  const float* rp2 = nullptr;
  if (NSEG >= 2) rp1 = s1 + (long)(i1 ? i1[erow] : (int)erow) * Hdim;
  if (NSEG >= 3) rp2 = s2 + (long)(i2 ? i2[erow] : (int)erow) * Hdim;

  auto aptr = [&](int m) -> const float* {
    const int seg = m >> 2;
    const float* rp = rp0;
    if (NSEG >= 2 && seg == 1) rp = rp1;
    if (NSEG >= 3 && seg == 2) rp = rp2;
    return rp + (m & 3) * 64 + w * 16;
  };

  auto loadA = [&](int m, float4* v) {
    const float* p = aptr(m);
#pragma unroll
    for (int i = 0; i < 4; ++i) v[i] = *(const float4*)(p + i * 4);
  };

  auto stageA = [&](int buf, const float4* v) {
    float in[16] = {v[0].x, v[0].y, v[0].z, v[0].w, v[1].x, v[1].y, v[1].z, v[1].w,
                    v[2].x, v[2].y, v[2].z, v[2].w, v[3].x, v[3].y, v[3].z, v[3].w};
    if constexpr (A3) {
      u16x8 th0, tl0, th1, tl1;
#pragma unroll
      for (int j = 0; j < 8; ++j) {
        BfPair p0 = split2t(in[j]);
        th0[j] = p0.hi; tl0[j] = p0.lo;
        BfPair p1 = split2t(in[j + 8]);
        th1[j] = p1.hi; tl1[j] = p1.lo;
      }
      *(u16x8*)&sm.u.ahi[buf][l][w * 16]     = th0;
      *(u16x8*)&sm.u.ahi[buf][l][w * 16 + 8] = th1;
      *(u16x8*)&sm.alo[buf][l][w * 16]       = tl0;
      *(u16x8*)&sm.alo[buf][l][w * 16 + 8]   = tl1;
    } else {
      u16x8 th0, th1;
#pragma unroll
      for (int j = 0; j < 8; ++j) {
        th0[j] = f2bf(in[j]);
        th1[j] = f2bf(in[j + 8]);
      }
      *(u16x8*)&sm.u.ahi[buf][l][w * 16]     = th0;
      *(u16x8*)&sm.u.ahi[buf][l][w * 16 + 8] = th1;
    }
  };

  auto loadB1 = [&](int t, bf16x8* bh, bf16x8* bl) {
#pragma unroll
    for (int n = 0; n < 4; ++n) {
      const long o = ((long)(t * 16 + w * 4 + n) * 64 + l) * 8;
      bh[n] = *(const bf16x8*)(W1Fh + o);
      bl[n] = *(const bf16x8*)(W1Fl + o);
    }
  };

  // ---------------- layer 1: cat(segs) @ W1 (R12 macro pipeline) ----------------
  f32x4 acc[4][4] = {};
  {
    float4 v[4];
    loadA(0, v);
    stageA(0, v);
  }
  float4 va[4], vb[4];
  loadA(1 < NU ? 1 : NU - 1, va);
  bf16x8 bhc[4], blc[4];
  loadB1(0, bhc, blc);

  for (int u = 0; u < NU; ++u) {
    bar_lds();
    loadA(u + 2 < NU ? u + 2 : NU - 1, vb);
    bf16x8 bhn[4], bln[4];
    loadB1(2 * u + 1 < NT ? 2 * u + 1 : NT - 1, bhn, bln);
    bf16x8 ah[4], al[4];
#pragma unroll
    for (int rb = 0; rb < 4; ++rb) {
      ah[rb] = *(const bf16x8*)&sm.u.ahi[u & 1][rb * 16 + lr][lg * 8];
      if constexpr (A3) al[rb] = *(const bf16x8*)&sm.alo[u & 1][rb * 16 + lr][lg * 8];
    }
    __builtin_amdgcn_s_setprio(1);
#pragma unroll
    for (int rb = 0; rb < 4; ++rb)
#pragma unroll
      for (int n = 0; n < 4; ++n) {
        acc[rb][n] = __builtin_amdgcn_mfma_f32_16x16x32_bf16(ah[rb], bhc[n], acc[rb][n], 0, 0, 0);
        acc[rb][n] = __builtin_amdgcn_mfma_f32_16x16x32_bf16(ah[rb], blc[n], acc[rb][n], 0, 0, 0);
        if constexpr (A3)
          acc[rb][n] = __builtin_amdgcn_mfma_f32_16x16x32_bf16(al[rb], bhc[n], acc[rb][n], 0, 0, 0);
      }
    __builtin_amdgcn_s_setprio(0);
    bf16x8 bh2[4], bl2[4];
    loadB1(2 * u + 2 < NT ? 2 * u + 2 : NT - 1, bh2, bl2);
#pragma unroll
    for (int rb = 0; rb < 4; ++rb) {
      ah[rb] = *(const bf16x8*)&sm.u.ahi[u & 1][rb * 16 + lr][32 + lg * 8];
      if constexpr (A3) al[rb] = *(const bf16x8*)&sm.alo[u & 1][rb * 16 + lr][32 + lg * 8];
    }
    __builtin_amdgcn_s_setprio(1);
#pragma unroll
    for (int rb = 0; rb < 4; ++rb)
#pragma unroll
      for (int n = 0; n < 4; ++n) {
        acc[rb][n] = __builtin_amdgcn_mfma_f32_16x16x32_bf16(ah[rb], bhn[n], acc[rb][n], 0, 0, 0);
        acc[rb][n] = __builtin_amdgcn_mfma_f32_16x16x32_bf16(ah[rb], bln[n], acc[rb][n], 0, 0, 0);
        if constexpr (A3)
          acc[rb][n] = __builtin_amdgcn_mfma_f32_16x16x32_bf16(al[rb], bhn[n], acc[rb][n], 0, 0, 0);
      }
    __builtin_amdgcn_s_setprio(0);
    if (u + 1 < NU) stageA((u + 1) & 1, va);
#pragma unroll
    for (int i = 0; i < 4; ++i) va[i] = vb[i];
#pragma unroll
    for (int n = 0; n < 4; ++n) { bhc[n] = bh2[n]; blc[n] = bl2[n]; }
  }

  bf16x8 b2hc[4], b2lc[4];
#pragma unroll
  for (int n = 0; n < 4; ++n) {
    const long o = ((long)(w * 4 + n) * 64 + l) * 8;
    b2hc[n] = *(const bf16x8*)(W2Fh + o);
    b2lc[n] = *(const bf16x8*)(W2Fl + o);
  }

  float bb1[4];
#pragma unroll
  for (int n = 0; n < 4; ++n) bb1[n] = b1[colbase + n * 16];
#pragma unroll
  for (int rb = 0; rb < 4; ++rb) {
#pragma unroll
    for (int n = 0; n < 4; ++n) {
      const int col = colbase + n * 16;
#pragma unroll
      for (int r = 0; r < 4; ++r) {
        const int row = rb * 16 + lg * 4 + r;
        float v = acc[rb][n][r] + bb1[n];
        v = v / (1.0f + __expf(-v));
        sm.hh[row * 256 + (col ^ hswz(row))] = f2bf(v);
      }
    }
  }
  bar_lds();

  f32x4 acc2[4][4] = {};
  for (int ks = 0; ks < 8; ++ks) {
    const int kn = (ks + 1 < 8) ? ks + 1 : ks;
    bf16x8 b2hn[4], b2ln[4];
#pragma unroll
    for (int n = 0; n < 4; ++n) {
      const long o = ((long)(kn * 16 + w * 4 + n) * 64 + l) * 8;
      b2hn[n] = *(const bf16x8*)(W2Fh + o);
      b2ln[n] = *(const bf16x8*)(W2Fl + o);
    }
    bf16x8 ah[4];
#pragma unroll
    for (int rb = 0; rb < 4; ++rb) {
      const int row = rb * 16 + lr;
      ah[rb] = *(const bf16x8*)&sm.hh[row * 256 + ((ks * 32 + lg * 8) ^ hswz(row))];
    }
    __builtin_amdgcn_s_setprio(1);
#pragma unroll
    for (int rb = 0; rb < 4; ++rb)
#pragma unroll
      for (int n = 0; n < 4; ++n) {
        acc2[rb][n] = __builtin_amdgcn_mfma_f32_16x16x32_bf16(ah[rb], b2hc[n], acc2[rb][n], 0, 0, 0);
        acc2[rb][n] = __builtin_amdgcn_mfma_f32_16x16x32_bf16(ah[rb], b2lc[n], acc2[rb][n], 0, 0, 0);
      }
    __builtin_amdgcn_s_setprio(0);
#pragma unroll
    for (int n = 0; n < 4; ++n) { b2hc[n] = b2hn[n]; b2lc[n] = b2ln[n]; }
  }
  __syncthreads();   // hh reads done; ahi/lnp union re-used below

  float bb2[4], gmv[4], btv[4];
#pragma unroll
  for (int n = 0; n < 4; ++n) {
    const int c = colbase + n * 16;
    bb2[n] = b2[c];
    gmv[n] = gamma[c];
    btv[n] = beta[c];
  }
  float psum[16];
#pragma unroll
  for (int rb = 0; rb < 4; ++rb)
#pragma unroll
    for (int r = 0; r < 4; ++r) {
      float s = 0.f;
#pragma unroll
      for (int n = 0; n < 4; ++n) s += acc2[rb][n][r] + bb2[n];
      psum[rb * 4 + r] = s;
    }
#pragma unroll
  for (int i = 0; i < 16; ++i) {
    psum[i] += __shfl_xor(psum[i], 1, 64);
    psum[i] += __shfl_xor(psum[i], 2, 64);
    psum[i] += __shfl_xor(psum[i], 4, 64);
    psum[i] += __shfl_xor(psum[i], 8, 64);
  }
  if (lr == 0) {
#pragma unroll
    for (int rb = 0; rb < 4; ++rb)
#pragma unroll
      for (int r = 0; r < 4; ++r)
        sm.u.lnp[w][rb * 16 + lg * 4 + r][0] = psum[rb * 4 + r];
  }
  __syncthreads();
  float mu[16];
#pragma unroll
  for (int rb = 0; rb < 4; ++rb)
#pragma unroll
    for (int r = 0; r < 4; ++r) {
      const int row = rb * 16 + lg * 4 + r;
      mu[rb * 4 + r] = (sm.u.lnp[0][row][0] + sm.u.lnp[1][row][0] +
                        sm.u.lnp[2][row][0] + sm.u.lnp[3][row][0]) * (1.0f / 256.0f);
    }
  float psq[16];
#pragma unroll
  for (int rb = 0; rb < 4; ++rb)
#pragma unroll
    for (int r = 0; r < 4; ++r) {
      float s = 0.f;
#pragma unroll
      for (int n = 0; n < 4; ++n) {
        const float d = acc2[rb][n][r] + bb2[n] - mu[rb * 4 + r];
        s += d * d;
      }
      psq[rb * 4 + r] = s;
    }
#pragma unroll
  for (int i = 0; i < 16; ++i) {
    psq[i] += __shfl_xor(psq[i], 1, 64);
    psq[i] += __shfl_xor(psq[i], 2, 64);
    psq[i] += __shfl_xor(psq[i], 4, 64);
    psq[i] += __shfl_xor(psq[i], 8, 64);
  }
  if (lr == 0) {
#pragma unroll
    for (int rb = 0; rb < 4; ++rb)
#pragma unroll
      for (int r = 0; r < 4; ++r)
        sm.u.lnp[w][rb * 16 + lg * 4 + r][1] = psq[rb * 4 + r];
  }
  __syncthreads();
#pragma unroll
  for (int rb = 0; rb < 4; ++rb) {
#pragma unroll
    for (int r = 0; r < 4; ++r) {
      const int row = rb * 16 + lg * 4 + r;
      const long grow = blockRow + row;
      if (grow >= M) continue;
      const float var = (sm.u.lnp[0][row][1] + sm.u.lnp[1][row][1] +
                         sm.u.lnp[2][row][1] + sm.u.lnp[3][row][1]) * (1.0f / 256.0f);
      const float rstd = 1.0f / sqrtf(var + 1e-5f);
      const float m = mu[rb * 4 + r];
      if constexpr (SCATTER) {
        const int d = scat[ord ? ord[grow] : grow];
        float* ap = agg + (long)d * Hdim;
#pragma unroll
        for (int n = 0; n < 4; ++n) {
          const int c = colbase + n * 16;
          atomicAdd(ap + c, (acc2[rb][n][r] + bb2[n] - m) * rstd * gmv[n] + btv[n]);
        }
      } else {
        const long o = grow * Hdim;
#pragma unroll
        for (int n = 0; n < 4; ++n) {
          const int c = colbase + n * 16;
          outp[o + c] = (acc2[rb][n][r] + bb2[n] - m) * rstd * gmv[n] + btv[n] + residual[o + c];
        }
      }
    }
  }
}

extern "C" void kernel_launch(void* const* d_in, const int* in_sizes, int n_in,
                              void* d_out, int out_size, void* d_ws, size_t ws_size,
                              hipStream_t stream) {
  const float* g2m   = (const float*)d_in[0];
  const float* gridf = (const float*)d_in[1];
  const float* meshf = (const float*)d_in[2];
  const int*   src   = (const int*)d_in[3];
  const int*   dst   = (const int*)d_in[4];
  const float* eW1 = (const float*)d_in[5];  const float* eb1 = (const float*)d_in[6];
  const float* eW2 = (const float*)d_in[7];  const float* eb2 = (const float*)d_in[8];
  const float* eg  = (const float*)d_in[9];  const float* ebt = (const float*)d_in[10];
  const float* sW1 = (const float*)d_in[11]; const float* sb1 = (const float*)d_in[12];
  const float* sW2 = (const float*)d_in[13]; const float* sb2 = (const float*)d_in[14];
  const float* sg  = (const float*)d_in[15]; const float* sbt = (const float*)d_in[16];
  const float* dW1 = (const float*)d_in[17]; const float* db1 = (const float*)d_in[18];
  const float* dW2 = (const float*)d_in[19]; const float* db2 = (const float*)d_in[20];
  const float* dg  = (const float*)d_in[21]; const float* dbt = (const float*)d_in[22];

  float* out_grid = (float*)d_out;
  float* out_mesh = out_grid + (long)NG_N * Hdim;

  unsigned short* p = (unsigned short*)d_ws;
  unsigned short* eW1Fh = p; p += 768 * 256;  unsigned short* eW1Fl = p; p += 768 * 256;
  unsigned short* eW2Fh = p; p += 256 * 256;  unsigned short* eW2Fl = p; p += 256 * 256;
  unsigned short* sW1Fh = p; p += 256 * 256;  unsigned short* sW1Fl = p; p += 256 * 256;
  unsigned short* sW2Fh = p; p += 256 * 256;  unsigned short* sW2Fl = p; p += 256 * 256;
  unsigned short* dW1Fh = p; p += 512 * 256;  unsigned short* dW1Fl = p; p += 512 * 256;
  unsigned short* dW2Fh = p; p += 256 * 256;  unsigned short* dW2Fl = p; p += 256 * 256;
  int* cnt   = (int*)p;
  int* off2  = cnt + NM_N;
  int* order = off2 + NM_N;

  auto WF = [&](const float* W, unsigned short* Fh, unsigned short* Fl, int K, int N) {
    int tot = K * N;
    wfrag_kernel<<<(tot + 255) / 256, 256, 0, stream>>>(W, Fh, Fl, K, N);
  };
  WF(eW1, eW1Fh, eW1Fl, 768, 256);
  WF(eW2, eW2Fh, eW2Fl, 256, 256);
  WF(sW1, sW1Fh, sW1Fl, 256, 256);
  WF(sW2, sW2Fh, sW2Fl, 256, 256);
  WF(dW1, dW1Fh, dW1Fl, 512, 256);
  WF(dW2, dW2Fh, dW2Fl, 256, 256);

  // build dst-sorted edge permutation
  (void)hipMemsetAsync(cnt, 0, (size_t)NM_N * sizeof(int), stream);
  hist_kernel<<<(E_N + 255) / 256, 256, 0, stream>>>(dst, cnt, E_N);
  scan_kernel<<<1, 1024, 0, stream>>>(cnt, off2, NM_N);
  fill_kernel<<<(E_N + 255) / 256, 256, 0, stream>>>(dst, off2, order, E_N);

  // zero the agg accumulator (mesh output region)
  (void)hipMemsetAsync(out_mesh, 0, (size_t)NM_N * Hdim * sizeof(float), stream);

  // edge MLP (dst-sorted): cat[g2m, grid[src], mesh[dst]] -> scatter into agg
  mlp_mfma<3, true, false><<<(E_N + 63) / 64, 256, 0, stream>>>(
      g2m, gridf, meshf, src, dst, E_N,
      eW1Fh, eW1Fl, eb1, eW2Fh, eW2Fl, eb2, eg, ebt,
      nullptr, nullptr, out_mesh, dst, order);

  // grid MLP: grid_new = grid + MLP(grid)
  mlp_mfma<1, false, true><<<(NG_N + 63) / 64, 256, 0, stream>>>(
      gridf, nullptr, nullptr, nullptr, nullptr, NG_N,
      sW1Fh, sW1Fl, sb1, sW2Fh, sW2Fl, sb2, sg, sbt,
      gridf, out_grid, nullptr, nullptr, nullptr);

  // mesh MLP: mesh_new = mesh + MLP(cat[agg, mesh])
  mlp_mfma<2, false, true><<<(NM_N + 63) / 64, 256, 0, stream>>>(
      out_mesh, meshf, nullptr, nullptr, nullptr, NM_N,
      dW1Fh, dW1Fl, db1, dW2Fh, dW2Fl, db2, dg, dbt,
      meshf, out_mesh, nullptr, nullptr, nullptr);
}

// Round 17
// 752.937 us; speedup vs baseline: 1.9485x; 1.9485x over previous
//
#include <hip/hip_runtime.h>

#define Hdim 256
static const int E_N  = 260640;
static const int NG_N = 65160;
static const int NM_N = 40962;

typedef __attribute__((ext_vector_type(8))) __bf16 bf16x8;
typedef __attribute__((ext_vector_type(8))) unsigned short u16x8;
typedef __attribute__((ext_vector_type(4))) float f32x4;

__device__ __forceinline__ unsigned short f2bf(float f) {
  unsigned u = __float_as_uint(f);
  u = (u + 0x7FFFu + ((u >> 16) & 1u)) >> 16;
  return (unsigned short)u;
}
__device__ __forceinline__ float bf2f(unsigned short h) {
  return __uint_as_float((unsigned)h << 16);
}
struct BfPair { unsigned short hi, lo; };
__device__ __forceinline__ BfPair split2(float f) {
  BfPair r;
  r.hi = f2bf(f);
  r.lo = f2bf(f - bf2f(r.hi));
  return r;
}
__device__ __forceinline__ BfPair split2t(float f) {
  unsigned u = __float_as_uint(f);
  BfPair r;
  r.hi = (unsigned short)(u >> 16);
  r.lo = f2bf(f - __uint_as_float(u & 0xffff0000u));
  return r;
}
__device__ __forceinline__ int hswz(int row) {
  return ((row & 7) << 3) ^ (((row >> 2) & 3) << 4);
}
__device__ __forceinline__ void bar_lds() {
  asm volatile("s_waitcnt lgkmcnt(0)" ::: "memory");
  __builtin_amdgcn_s_barrier();
}

// W [K][N=256] f32 -> fragment-major split-bf16 (see R12)
__global__ void wfrag_kernel(const float* __restrict__ W,
                             unsigned short* __restrict__ Fh,
                             unsigned short* __restrict__ Fl, int K, int N) {
  int i = blockIdx.x * 256 + threadIdx.x;
  if (i >= K * N) return;
  int k = i / N;
  int col = i - k * N;
  BfPair p = split2(W[i]);
  int t = k >> 5, rem = k & 31;
  int lg = rem >> 3, j = rem & 7;
  int cb = col >> 4, lr = col & 15;
  long o = ((long)(t * 16 + cb) * 64 + (lg * 16 + lr)) * 8 + j;
  Fh[o] = p.hi;
  Fl[o] = p.lo;
}

// edge (A3=false): union(ahi 18432, lnp 2048) + hh 32768 = 51.2 KB -> 3 blocks/CU
// grid/mesh (A3=true): + alo 18432 = 69.6 KB -> 2 blocks/CU
template <bool A3>
struct SMem {
  union {
    unsigned short ahi[2][64][72];
    float lnp[4][64][2];
  } u;
  unsigned short alo[A3 ? 2 : 1][A3 ? 64 : 1][A3 ? 72 : 1];
  unsigned short hh[64 * 256];             // XOR-swizzled rows
};

// out = LN(silu(cat(segs)@W1+b1)@W2+b2)*g+b  [+residual | atomic scatter]
// layer1: A3 ? 3-product : 2-product; layer2: 2-product. Fragment-major W.
// NOTE: bounds stays (256,2) — min-waves hint only CAPS registers; the 3rd
// block arrives via LDS (51.7KB) + natural 160-reg allocation (R15 lesson:
// bounds=3 squeezed regalloc into scratch spills = +2.5GB HBM traffic).
template <int NSEG, bool SCATTER, bool A3>
__launch_bounds__(256, 2)
__global__ void mlp_mfma(
    const float* s0, const float* s1, const float* s2,
    const int* __restrict__ i1, const int* __restrict__ i2, int M,
    const unsigned short* __restrict__ W1Fh, const unsigned short* __restrict__ W1Fl,
    const float* __restrict__ b1,
    const unsigned short* __restrict__ W2Fh, const unsigned short* __restrict__ W2Fl,
    const float* __restrict__ b2,
    const float* __restrict__ gamma, const float* __restrict__ beta,
    const float* residual, float* outp,
    float* agg, const int* __restrict__ scat) {
  constexpr int K1 = NSEG * 256;
  constexpr int NT = K1 / 32;
  constexpr int NU = K1 / 64;
  __shared__ SMem<A3> sm;

  const int tid = threadIdx.x;
  const int w = tid >> 6;
  const int l = tid & 63;
  const int lr = l & 15;
  const int lg = l >> 4;
  const int colbase = w * 64 + lr;
  const long blockRow = (long)blockIdx.x * 64;

  const long grow_s = blockRow + l;
  const long growc = grow_s < M ? grow_s : (long)(M - 1);
  const float* rp0 = s0 + growc * Hdim;
  const float* rp1 = nullptr;
  const float* rp2 = nullptr;
  if (NSEG >= 2) rp1 = s1 + (long)(i1 ? i1[growc] : (int)growc) * Hdim;
  if (NSEG >= 3) rp2 = s2 + (long)(i2 ? i2[growc] : (int)growc) * Hdim;

  auto aptr = [&](int m) -> const float* {
    const int seg = m >> 2;
    const float* rp = rp0;
    if (NSEG >= 2 && seg == 1) rp = rp1;
    if (NSEG >= 3 && seg == 2) rp = rp2;
    return rp + (m & 3) * 64 + w * 16;
  };

  auto loadA = [&](int m, float4* v) {
    const float* p = aptr(m);
#pragma unroll
    for (int i = 0; i < 4; ++i) v[i] = *(const float4*)(p + i * 4);
  };

  auto stageA = [&](int buf, const float4* v) {
    float in[16] = {v[0].x, v[0].y, v[0].z, v[0].w, v[1].x, v[1].y, v[1].z, v[1].w,
                    v[2].x, v[2].y, v[2].z, v[2].w, v[3].x, v[3].y, v[3].z, v[3].w};
    if constexpr (A3) {
      u16x8 th0, tl0, th1, tl1;
#pragma unroll
      for (int j = 0; j < 8; ++j) {
        BfPair p0 = split2t(in[j]);
        th0[j] = p0.hi; tl0[j] = p0.lo;
        BfPair p1 = split2t(in[j + 8]);
        th1[j] = p1.hi; tl1[j] = p1.lo;
      }
      *(u16x8*)&sm.u.ahi[buf][l][w * 16]     = th0;
      *(u16x8*)&sm.u.ahi[buf][l][w * 16 + 8] = th1;
      *(u16x8*)&sm.alo[buf][l][w * 16]       = tl0;
      *(u16x8*)&sm.alo[buf][l][w * 16 + 8]   = tl1;
    } else {
      u16x8 th0, th1;
#pragma unroll
      for (int j = 0; j < 8; ++j) {
        th0[j] = f2bf(in[j]);
        th1[j] = f2bf(in[j + 8]);
      }
      *(u16x8*)&sm.u.ahi[buf][l][w * 16]     = th0;
      *(u16x8*)&sm.u.ahi[buf][l][w * 16 + 8] = th1;
    }
  };

  auto loadB1 = [&](int t, bf16x8* bh, bf16x8* bl) {
#pragma unroll
    for (int n = 0; n < 4; ++n) {
      const long o = ((long)(t * 16 + w * 4 + n) * 64 + l) * 8;
      bh[n] = *(const bf16x8*)(W1Fh + o);
      bl[n] = *(const bf16x8*)(W1Fl + o);
    }
  };

  // ---------------- layer 1: cat(segs) @ W1 (R12 macro pipeline) ----------------
  f32x4 acc[4][4] = {};
  {
    float4 v[4];
    loadA(0, v);
    stageA(0, v);
  }
  float4 va[4], vb[4];               // A(u+1), A(u+2) in flight
  loadA(1 < NU ? 1 : NU - 1, va);
  bf16x8 bhc[4], blc[4];
  loadB1(0, bhc, blc);

  for (int u = 0; u < NU; ++u) {
    bar_lds();                       // buf[u&1] visible; no vmcnt drain
    loadA(u + 2 < NU ? u + 2 : NU - 1, vb);
    // ---- k-step s=0 (t = 2u) ----
    bf16x8 bhn[4], bln[4];
    loadB1(2 * u + 1 < NT ? 2 * u + 1 : NT - 1, bhn, bln);
    bf16x8 ah[4], al[4];
#pragma unroll
    for (int rb = 0; rb < 4; ++rb) {
      ah[rb] = *(const bf16x8*)&sm.u.ahi[u & 1][rb * 16 + lr][lg * 8];
      if constexpr (A3) al[rb] = *(const bf16x8*)&sm.alo[u & 1][rb * 16 + lr][lg * 8];
    }
    __builtin_amdgcn_s_setprio(1);
#pragma unroll
    for (int rb = 0; rb < 4; ++rb)
#pragma unroll
      for (int n = 0; n < 4; ++n) {
        acc[rb][n] = __builtin_amdgcn_mfma_f32_16x16x32_bf16(ah[rb], bhc[n], acc[rb][n], 0, 0, 0);
        acc[rb][n] = __builtin_amdgcn_mfma_f32_16x16x32_bf16(ah[rb], blc[n], acc[rb][n], 0, 0, 0);
        if constexpr (A3)
          acc[rb][n] = __builtin_amdgcn_mfma_f32_16x16x32_bf16(al[rb], bhc[n], acc[rb][n], 0, 0, 0);
      }
    __builtin_amdgcn_s_setprio(0);
    // ---- k-step s=1 (t = 2u+1) ----
    bf16x8 bh2[4], bl2[4];
    loadB1(2 * u + 2 < NT ? 2 * u + 2 : NT - 1, bh2, bl2);
#pragma unroll
    for (int rb = 0; rb < 4; ++rb) {
      ah[rb] = *(const bf16x8*)&sm.u.ahi[u & 1][rb * 16 + lr][32 + lg * 8];
      if constexpr (A3) al[rb] = *(const bf16x8*)&sm.alo[u & 1][rb * 16 + lr][32 + lg * 8];
    }
    __builtin_amdgcn_s_setprio(1);
#pragma unroll
    for (int rb = 0; rb < 4; ++rb)
#pragma unroll
      for (int n = 0; n < 4; ++n) {
        acc[rb][n] = __builtin_amdgcn_mfma_f32_16x16x32_bf16(ah[rb], bhn[n], acc[rb][n], 0, 0, 0);
        acc[rb][n] = __builtin_amdgcn_mfma_f32_16x16x32_bf16(ah[rb], bln[n], acc[rb][n], 0, 0, 0);
        if constexpr (A3)
          acc[rb][n] = __builtin_amdgcn_mfma_f32_16x16x32_bf16(al[rb], bhn[n], acc[rb][n], 0, 0, 0);
      }
    __builtin_amdgcn_s_setprio(0);
    // ---- stage A(u+1) ----
    if (u + 1 < NU) stageA((u + 1) & 1, va);
#pragma unroll
    for (int i = 0; i < 4; ++i) va[i] = vb[i];
#pragma unroll
    for (int n = 0; n < 4; ++n) { bhc[n] = bh2[n]; blc[n] = bl2[n]; }
  }

  // B2(0) prefetch early
  bf16x8 b2hc[4], b2lc[4];
#pragma unroll
  for (int n = 0; n < 4; ++n) {
    const long o = ((long)(w * 4 + n) * 64 + l) * 8;
    b2hc[n] = *(const bf16x8*)(W2Fh + o);
    b2lc[n] = *(const bf16x8*)(W2Fl + o);
  }

  // ---------------- bias1 + SiLU -> h (bf16 hi, XOR-swizzled) ----------------
  float bb1[4];
#pragma unroll
  for (int n = 0; n < 4; ++n) bb1[n] = b1[colbase + n * 16];
#pragma unroll
  for (int rb = 0; rb < 4; ++rb) {
#pragma unroll
    for (int n = 0; n < 4; ++n) {
      const int col = colbase + n * 16;
#pragma unroll
      for (int r = 0; r < 4; ++r) {
        const int row = rb * 16 + lg * 4 + r;
        float v = acc[rb][n][r] + bb1[n];
        v = v / (1.0f + __expf(-v));
        sm.hh[row * 256 + (col ^ hswz(row))] = f2bf(v);
      }
    }
  }
  bar_lds();

  // ---------------- layer 2: h @ W2 (2-product, no barriers) ----------------
  f32x4 acc2[4][4] = {};
  for (int ks = 0; ks < 8; ++ks) {
    const int kn = (ks + 1 < 8) ? ks + 1 : ks;
    bf16x8 b2hn[4], b2ln[4];
#pragma unroll
    for (int n = 0; n < 4; ++n) {
      const long o = ((long)(kn * 16 + w * 4 + n) * 64 + l) * 8;
      b2hn[n] = *(const bf16x8*)(W2Fh + o);
      b2ln[n] = *(const bf16x8*)(W2Fl + o);
    }
    bf16x8 ah[4];
#pragma unroll
    for (int rb = 0; rb < 4; ++rb) {
      const int row = rb * 16 + lr;
      ah[rb] = *(const bf16x8*)&sm.hh[row * 256 + ((ks * 32 + lg * 8) ^ hswz(row))];
    }
    __builtin_amdgcn_s_setprio(1);
#pragma unroll
    for (int rb = 0; rb < 4; ++rb)
#pragma unroll
      for (int n = 0; n < 4; ++n) {
        acc2[rb][n] = __builtin_amdgcn_mfma_f32_16x16x32_bf16(ah[rb], b2hc[n], acc2[rb][n], 0, 0, 0);
        acc2[rb][n] = __builtin_amdgcn_mfma_f32_16x16x32_bf16(ah[rb], b2lc[n], acc2[rb][n], 0, 0, 0);
      }
    __builtin_amdgcn_s_setprio(0);
#pragma unroll
    for (int n = 0; n < 4; ++n) { b2hc[n] = b2hn[n]; b2lc[n] = b2ln[n]; }
  }
  __syncthreads();   // hh reads done; ahi/lnp union re-used below

  // ---------------- LayerNorm in registers (two-pass) + epilogue ----------------
  float bb2[4], gmv[4], btv[4];
#pragma unroll
  for (int n = 0; n < 4; ++n) {
    const int c = colbase + n * 16;
    bb2[n] = b2[c];
    gmv[n] = gamma[c];
    btv[n] = beta[c];
  }
  float psum[16];
#pragma unroll
  for (int rb = 0; rb < 4; ++rb)
#pragma unroll
    for (int r = 0; r < 4; ++r) {
      float s = 0.f;
#pragma unroll
      for (int n = 0; n < 4; ++n) s += acc2[rb][n][r] + bb2[n];
      psum[rb * 4 + r] = s;
    }
#pragma unroll
  for (int i = 0; i < 16; ++i) {
    psum[i] += __shfl_xor(psum[i], 1, 64);
    psum[i] += __shfl_xor(psum[i], 2, 64);
    psum[i] += __shfl_xor(psum[i], 4, 64);
    psum[i] += __shfl_xor(psum[i], 8, 64);
  }
  if (lr == 0) {
#pragma unroll
    for (int rb = 0; rb < 4; ++rb)
#pragma unroll
      for (int r = 0; r < 4; ++r)
        sm.u.lnp[w][rb * 16 + lg * 4 + r][0] = psum[rb * 4 + r];
  }
  __syncthreads();
  float mu[16];
#pragma unroll
  for (int rb = 0; rb < 4; ++rb)
#pragma unroll
    for (int r = 0; r < 4; ++r) {
      const int row = rb * 16 + lg * 4 + r;
      mu[rb * 4 + r] = (sm.u.lnp[0][row][0] + sm.u.lnp[1][row][0] +
                        sm.u.lnp[2][row][0] + sm.u.lnp[3][row][0]) * (1.0f / 256.0f);
    }
  float psq[16];
#pragma unroll
  for (int rb = 0; rb < 4; ++rb)
#pragma unroll
    for (int r = 0; r < 4; ++r) {
      float s = 0.f;
#pragma unroll
      for (int n = 0; n < 4; ++n) {
        const float d = acc2[rb][n][r] + bb2[n] - mu[rb * 4 + r];
        s += d * d;
      }
      psq[rb * 4 + r] = s;
    }
#pragma unroll
  for (int i = 0; i < 16; ++i) {
    psq[i] += __shfl_xor(psq[i], 1, 64);
    psq[i] += __shfl_xor(psq[i], 2, 64);
    psq[i] += __shfl_xor(psq[i], 4, 64);
    psq[i] += __shfl_xor(psq[i], 8, 64);
  }
  if (lr == 0) {
#pragma unroll
    for (int rb = 0; rb < 4; ++rb)
#pragma unroll
      for (int r = 0; r < 4; ++r)
        sm.u.lnp[w][rb * 16 + lg * 4 + r][1] = psq[rb * 4 + r];
  }
  __syncthreads();
#pragma unroll
  for (int rb = 0; rb < 4; ++rb) {
#pragma unroll
    for (int r = 0; r < 4; ++r) {
      const int row = rb * 16 + lg * 4 + r;
      const long grow = blockRow + row;
      if (grow >= M) continue;
      const float var = (sm.u.lnp[0][row][1] + sm.u.lnp[1][row][1] +
                         sm.u.lnp[2][row][1] + sm.u.lnp[3][row][1]) * (1.0f / 256.0f);
      const float rstd = 1.0f / sqrtf(var + 1e-5f);
      const float m = mu[rb * 4 + r];
      if constexpr (SCATTER) {
        const int d = scat[grow];
        float* ap = agg + (long)d * Hdim;
#pragma unroll
        for (int n = 0; n < 4; ++n) {
          const int c = colbase + n * 16;
          atomicAdd(ap + c, (acc2[rb][n][r] + bb2[n] - m) * rstd * gmv[n] + btv[n]);
        }
      } else {
        const long o = grow * Hdim;
#pragma unroll
        for (int n = 0; n < 4; ++n) {
          const int c = colbase + n * 16;
          outp[o + c] = (acc2[rb][n][r] + bb2[n] - m) * rstd * gmv[n] + btv[n] + residual[o + c];
        }
      }
    }
  }
}

extern "C" void kernel_launch(void* const* d_in, const int* in_sizes, int n_in,
                              void* d_out, int out_size, void* d_ws, size_t ws_size,
                              hipStream_t stream) {
  const float* g2m   = (const float*)d_in[0];
  const float* gridf = (const float*)d_in[1];
  const float* meshf = (const float*)d_in[2];
  const int*   src   = (const int*)d_in[3];
  const int*   dst   = (const int*)d_in[4];
  const float* eW1 = (const float*)d_in[5];  const float* eb1 = (const float*)d_in[6];
  const float* eW2 = (const float*)d_in[7];  const float* eb2 = (const float*)d_in[8];
  const float* eg  = (const float*)d_in[9];  const float* ebt = (const float*)d_in[10];
  const float* sW1 = (const float*)d_in[11]; const float* sb1 = (const float*)d_in[12];
  const float* sW2 = (const float*)d_in[13]; const float* sb2 = (const float*)d_in[14];
  const float* sg  = (const float*)d_in[15]; const float* sbt = (const float*)d_in[16];
  const float* dW1 = (const float*)d_in[17]; const float* db1 = (const float*)d_in[18];
  const float* dW2 = (const float*)d_in[19]; const float* db2 = (const float*)d_in[20];
  const float* dg  = (const float*)d_in[21]; const float* dbt = (const float*)d_in[22];

  float* out_grid = (float*)d_out;
  float* out_mesh = out_grid + (long)NG_N * Hdim;

  unsigned short* p = (unsigned short*)d_ws;
  unsigned short* eW1Fh = p; p += 768 * 256;  unsigned short* eW1Fl = p; p += 768 * 256;
  unsigned short* eW2Fh = p; p += 256 * 256;  unsigned short* eW2Fl = p; p += 256 * 256;
  unsigned short* sW1Fh = p; p += 256 * 256;  unsigned short* sW1Fl = p; p += 256 * 256;
  unsigned short* sW2Fh = p; p += 256 * 256;  unsigned short* sW2Fl = p; p += 256 * 256;
  unsigned short* dW1Fh = p; p += 512 * 256;  unsigned short* dW1Fl = p; p += 512 * 256;
  unsigned short* dW2Fh = p; p += 256 * 256;  unsigned short* dW2Fl = p; p += 256 * 256;

  auto WF = [&](const float* W, unsigned short* Fh, unsigned short* Fl, int K, int N) {
    int tot = K * N;
    wfrag_kernel<<<(tot + 255) / 256, 256, 0, stream>>>(W, Fh, Fl, K, N);
  };
  WF(eW1, eW1Fh, eW1Fl, 768, 256);
  WF(eW2, eW2Fh, eW2Fl, 256, 256);
  WF(sW1, sW1Fh, sW1Fl, 256, 256);
  WF(sW2, sW2Fh, sW2Fl, 256, 256);
  WF(dW1, dW1Fh, dW1Fl, 512, 256);
  WF(dW2, dW2Fh, dW2Fl, 256, 256);

  (void)hipMemsetAsync(out_mesh, 0, (size_t)NM_N * Hdim * sizeof(float), stream);

  mlp_mfma<3, true, false><<<(E_N + 63) / 64, 256, 0, stream>>>(
      g2m, gridf, meshf, src, dst, E_N,
      eW1Fh, eW1Fl, eb1, eW2Fh, eW2Fl, eb2, eg, ebt,
      nullptr, nullptr, out_mesh, dst);

  mlp_mfma<1, false, true><<<(NG_N + 63) / 64, 256, 0, stream>>>(
      gridf, nullptr, nullptr, nullptr, nullptr, NG_N,
      sW1Fh, sW1Fl, sb1, sW2Fh, sW2Fl, sb2, sg, sbt,
      gridf, out_grid, nullptr, nullptr);

  mlp_mfma<2, false, true><<<(NM_N + 63) / 64, 256, 0, stream>>>(
      out_mesh, meshf, nullptr, nullptr, nullptr, NM_N,
      dW1Fh, dW1Fl, db1, dW2Fh, dW2Fl, db2, dg, dbt,
      meshf, out_mesh, nullptr, nullptr);
}